// Round 8
// baseline (12399.673 us; speedup 1.0000x reference)
//
#include <hip/hip_runtime.h>

#define L_SEQ 128
#define BATCH 512
#define DIM   512

typedef __attribute__((ext_vector_type(8))) short bf16x8;
typedef __attribute__((ext_vector_type(4))) float f32x4;
typedef unsigned short ushort_t;

#define MFMA16(a,b,c) __builtin_amdgcn_mfma_f32_16x16x32_bf16((a),(b),(c),0,0,0)

__device__ __forceinline__ ushort_t f2bf(float f) {
  union { float f; unsigned u; } v; v.f = f;
  unsigned u = v.u;
  unsigned r = (u + 0x7FFFu + ((u >> 16) & 1u)) >> 16;  // RNE
  return (ushort_t)r;
}
__device__ __forceinline__ float bf2f(ushort_t b) {
  union { unsigned u; float f; } v; v.u = ((unsigned)b) << 16;
  return v.f;
}
// byte offset into a [16][512] bf16 image, row stride 1024B, XOR-swizzled 16B chunks
__device__ __forceinline__ int aoff(int r, int k) {
  return (r << 10) + ((((k >> 3) ^ (r & 7)) << 4) | ((k & 7) << 1));
}
__device__ __forceinline__ float tanh_f(float x) {
  x = fminf(fmaxf(x, -15.f), 15.f);
  float e = __expf(2.f * x);
  return (e - 1.f) / (e + 1.f);
}
__device__ __forceinline__ float sigm_f(float x) {
  x = fminf(fmaxf(x, -30.f), 30.f);
  return 1.f / (1.f + __expf(-x));
}
__device__ __forceinline__ void barrier_nd() {   // lgkm-only barrier: vmcnt stays in flight
  asm volatile("s_waitcnt lgkmcnt(0)" ::: "memory");
  __builtin_amdgcn_s_barrier();
}

// ============================================================================
// Weight "slice image" layout (per matrix, 512x512 bf16 = 262144 ushorts):
//   elem(c,k) at: m*262144 + s*16384 + w*1024 + g*256 + cc*8 + j
//   with c = w*32 + cc(0..31), k = s*32 + g*8 + j.  Per (s,w): 2KB contiguous.
//   Per lane (lg,lr): p-frag (cols w*32+lr)  at ushort w*1024+lg*256+lr*8
//                     q-frag (cols w*32+16+lr) at +128 ushorts (+256B).
// m: 0:W1 1:W2 2:Whr 3:Whz 4:Whn 5:Wir 6:Wiz 7:Win
// ws map (ushorts): [0] weights 2097152 | [2097152] gib bf16 gi[L][B][1536]
// ============================================================================

__global__ __launch_bounds__(256) void prep_w(const float* __restrict__ W1,
                                              const float* __restrict__ W2,
                                              const float* __restrict__ Whh,
                                              const float* __restrict__ Wih,
                                              ushort_t* __restrict__ wsb) {
  unsigned idx = blockIdx.x * 256u + threadIdx.x;   // 0 .. 2097151
  unsigned m  = idx >> 18;
  unsigned r  = idx & 262143u;
  unsigned s  = r >> 14;
  unsigned r1 = r & 16383u;
  unsigned w  = r1 >> 10;
  unsigned r2 = r1 & 1023u;
  unsigned g  = r2 >> 8;
  unsigned r3 = r2 & 255u;
  unsigned cc = r3 >> 3;
  unsigned j  = r3 & 7u;
  unsigned c  = w * 32u + cc;
  unsigned k  = s * 32u + g * 8u + j;
  float v;
  if (m == 0)      v = W1[c * 512u + k];
  else if (m == 1) v = W2[c * 512u + k];
  else if (m < 5)  v = Whh[((m - 2u) * 512u + c) * 512u + k];
  else             v = Wih[((m - 5u) * 512u + c) * 512u + k];
  wsb[idx] = f2bf(v);
}

// ---- precompute gi[i][b][0:1536] = emb[x[b,i]] @ W_ih^T + b_ih  (bf16, nt stores) ----
__global__ __launch_bounds__(256) void gi_gemm(const float* __restrict__ emb,
                                               const int* __restrict__ x,
                                               const float* __restrict__ bih,
                                               const ushort_t* __restrict__ wsb,
                                               ushort_t* __restrict__ gib) {
  __shared__ __align__(16) unsigned char As[64 * 1024];
  const int tid = threadIdx.x;
  const int mb = blockIdx.x;            // 0..1023
  const int nb = blockIdx.y;            // 0..5
  const int i = (mb * 64) >> 9;
  const int brow0 = (mb * 64) & 511;
  {
    int r = tid >> 2;
    int xv = x[(brow0 + r) * L_SEQ + i];
    const float4* er4 = (const float4*)(emb + (size_t)xv * DIM);
#pragma unroll
    for (int cc = 0; cc < 16; ++cc) {
      int c = (tid & 3) * 16 + cc;
      float4 fa = er4[c * 2], fb = er4[c * 2 + 1];
      union { ushort_t u[8]; bf16x8 v; } pk;
      pk.u[0] = f2bf(fa.x); pk.u[1] = f2bf(fa.y); pk.u[2] = f2bf(fa.z); pk.u[3] = f2bf(fa.w);
      pk.u[4] = f2bf(fb.x); pk.u[5] = f2bf(fb.y); pk.u[6] = f2bf(fb.z); pk.u[7] = f2bf(fb.w);
      *(bf16x8*)(As + aoff(r, c * 8)) = pk.v;
    }
  }
  __syncthreads();
  const int wave = tid >> 6, lane = tid & 63;
  const int lr = lane & 15, lg = lane >> 4;
  const int ncol0 = nb * 256 + wave * 64;
  const int gate = nb >> 1;
  const ushort_t* wimg = wsb + (5u + (unsigned)gate) * 262144u;
  int bofs[4];
#pragma unroll
  for (int nf = 0; nf < 4; ++nf) {
    int cg = (nb & 1) * 256 + wave * 64 + nf * 16 + lr;  // gate-local col
    bofs[nf] = (cg >> 5) * 1024 + (cg & 31) * 8 + lg * 256;
  }
  f32x4 acc[4][4];
  f32x4 z = {0.f, 0.f, 0.f, 0.f};
#pragma unroll
  for (int mf = 0; mf < 4; ++mf)
#pragma unroll
    for (int nf = 0; nf < 4; ++nf) acc[mf][nf] = z;
#pragma unroll
  for (int kf = 0; kf < 16; ++kf) {
    bf16x8 a[4];
#pragma unroll
    for (int mf = 0; mf < 4; ++mf)
      a[mf] = *(const bf16x8*)(As + aoff((mf << 4) + lr, (kf << 5) + (lg << 3)));
#pragma unroll
    for (int nf = 0; nf < 4; ++nf) {
      bf16x8 b = *(const bf16x8*)(wimg + kf * 16384 + bofs[nf]);
#pragma unroll
      for (int mf = 0; mf < 4; ++mf) acc[mf][nf] = MFMA16(a[mf], b, acc[mf][nf]);
    }
  }
#pragma unroll
  for (int nf = 0; nf < 4; ++nf) {
    int col = ncol0 + (nf << 4) + lr;
    float bb = bih[col];
#pragma unroll
    for (int mf = 0; mf < 4; ++mf)
#pragma unroll
      for (int j = 0; j < 4; ++j) {
        int row = (mf << 4) + (lg << 2) + j;
        __builtin_nontemporal_store(f2bf(acc[mf][nf][j] + bb),
            gib + (size_t)(i * BATCH + brow0 + row) * 1536 + col);
      }
  }
}

// ============================================================================
// scan: 32 WGs x 1024 thr (16 waves, 32 cols each).  Weights stream L2->VGPR
// via asm global_load_dwordx4, depth-4 per-wave register ring, steady vmcnt(6),
// cursor chained across all 11 phases/step; barriers never drain vmcnt.
// ============================================================================

#define ISSUE_SL(BASE, S, Q) do { \
    const ushort_t* a_ = (BASE) + (unsigned)(S) * 16384u; \
    asm volatile("global_load_dwordx4 %0, %2, off\n\t" \
                 "global_load_dwordx4 %1, %2, off offset:256" \
                 : "=&v"(Rr[Q][0]), "=&v"(Rr[Q][1]) : "v"(a_) : "memory"); \
  } while (0)

#define CONS1(IMG, Q, SS, VM) do { \
    asm volatile("s_waitcnt vmcnt(" #VM ")" ::: "memory"); \
    __builtin_amdgcn_sched_barrier(0); \
    bf16x8 a_ = *(const bf16x8*)((IMG) + (lr << 10) + ((((SS) * 4 + lg) ^ (lr & 7)) << 4)); \
    acc[0] = MFMA16(a_, Rr[Q][0], acc[0]); \
    acc[1] = MFMA16(a_, Rr[Q][1], acc[1]); } while (0)

#define PH_STEADY(IMG, CUR, NXT) do { \
    acc[0] = z4; acc[1] = z4; \
    _Pragma("unroll") \
    for (int kf_ = 0; kf_ < 16; ++kf_) { \
      CONS1(IMG, kf_ & 3, kf_, 6); \
      if (kf_ < 12) ISSUE_SL(CUR, kf_ + 4, kf_ & 3); \
      else          ISSUE_SL(NXT, kf_ - 12, kf_ & 3); \
    } } while (0)

#define PH_DRAIN(IMG, CUR) do { \
    acc[0] = z4; acc[1] = z4; \
    _Pragma("unroll") \
    for (int kf_ = 0; kf_ < 12; ++kf_) { CONS1(IMG, kf_ & 3, kf_, 6); ISSUE_SL(CUR, kf_ + 4, kf_ & 3); } \
    CONS1(IMG, 0, 12, 6); CONS1(IMG, 1, 13, 4); CONS1(IMG, 2, 14, 2); CONS1(IMG, 3, 15, 0); \
  } while (0)

#define PROLOGUE4(BASE) do { ISSUE_SL(BASE,0,0); ISSUE_SL(BASE,1,1); \
                             ISSUE_SL(BASE,2,2); ISSUE_SL(BASE,3,3); } while (0)

__global__ __launch_bounds__(1024, 4) void scan_kernel(
    const float* __restrict__ t, const int* __restrict__ x,
    const ushort_t* __restrict__ wsb,
    const float* __restrict__ b1g, const float* __restrict__ b2g,
    const float* __restrict__ bhhg,
    const ushort_t* __restrict__ gib, float* __restrict__ out) {
  __shared__ __align__(16) unsigned char S0[16 * 1024];
  __shared__ __align__(16) unsigned char S1[16 * 1024];
  __shared__ float b1s[512], b2s[512], bhhs[1536];

  const int tid = threadIdx.x;
  const int wave = tid >> 6, lane = tid & 63;
  const int lr = lane & 15, lg = lane >> 4;
  const int n0 = wave * 32;
  const int b0 = blockIdx.x * 16;

  const ushort_t* wl = wsb + (unsigned)wave * 1024u + (unsigned)lg * 256u + (unsigned)lr * 8u;
  const ushort_t* base_w1 = wl;
  const ushort_t* base_w2 = wl + 262144u;
  const ushort_t* base_wr = wl + 2u * 262144u;
  const ushort_t* base_wz = wl + 3u * 262144u;
  const ushort_t* base_wn = wl + 4u * 262144u;

  for (int q = tid; q < 512; q += 1024) { b1s[q] = b1g[q]; b2s[q] = b2g[q]; }
  for (int q = tid; q < 1536; q += 1024) bhhs[q] = bhhg[q];
  { bf16x8 zz = {0, 0, 0, 0, 0, 0, 0, 0}; *(bf16x8*)(S0 + tid * 16) = zz; }
  __syncthreads();

  float h[2][4];
#pragma unroll
  for (int nf = 0; nf < 2; ++nf)
#pragma unroll
    for (int j = 0; j < 4; ++j) h[nf][j] = 0.f;

  // step-0 scalars (ring empty here; plain loads safe)
  float dtj[4], mj[4];
#pragma unroll
  for (int j = 0; j < 4; ++j) {
    int b = b0 + lg * 4 + j;
    mj[j] = (x[b * L_SEQ + 0] != 0) ? 1.f : 0.f;
    dtj[j] = 1e-6f;
  }

  bf16x8 Rr[4][2];
  f32x4 acc[2];
  const f32x4 z4 = {0.f, 0.f, 0.f, 0.f};

  for (int i = 0; i < L_SEQ; ++i) {
    if (i > 0) PROLOGUE4(base_w1); else PROLOGUE4(base_wr);
    barrier_nd();                                  // prev-step S0 writes visible

    if (i > 0) {
      float ksum[2][4] = {};
#pragma unroll 1
      for (int s4 = 0; s4 < 4; ++s4) {
        // ---- W1 @ eval-point image (S0) ----
        PH_STEADY(S0, base_w1, base_w2);
#pragma unroll
        for (int nf = 0; nf < 2; ++nf) {
          int col = n0 + nf * 16 + lr; float bb = b1s[col];
#pragma unroll
          for (int j = 0; j < 4; ++j)
            *(ushort_t*)(S1 + aoff(lg * 4 + j, col)) = f2bf(tanh_f(acc[nf][j] + bb));
        }
        barrier_nd();                              // u visible; S0 reads done
        // ---- W2 @ u image (S1) ----
        const ushort_t* nxt = (s4 < 3) ? base_w1 : base_wr;
        PH_STEADY(S1, base_w2, nxt);
        const float wk = (s4 == 0 || s4 == 3) ? 1.f : 2.f;
        const float cs = (s4 < 2) ? 0.5f : 1.f;
#pragma unroll
        for (int nf = 0; nf < 2; ++nf) {
          int col = n0 + nf * 16 + lr; float bb = b2s[col];
#pragma unroll
          for (int j = 0; j < 4; ++j) {
            float kv = acc[nf][j] + bb;
            ksum[nf][j] += wk * kv;
            float nv;
            if (s4 < 3) {
              nv = h[nf][j] + cs * dtj[j] * kv;    // next RK4 eval point
            } else {
              float hev = h[nf][j] + dtj[j] * (1.f / 6.f) * ksum[nf][j];
              nv = (mj[j] > 0.5f) ? hev : h[nf][j];
              h[nf][j] = nv;                        // h_pre for GRU
            }
            *(ushort_t*)(S0 + aoff(lg * 4 + j, col)) = f2bf(nv);
          }
        }
        barrier_nd();                              // next eval-point image visible
      }
    }

    // ---- GRU gate matmuls (all read S0 = h_pre image; no barriers needed) ----
    f32x4 gh0[2], gh1[2], gh2[2];
    PH_STEADY(S0, base_wr, base_wz); gh0[0] = acc[0]; gh0[1] = acc[1];
    PH_STEADY(S0, base_wz, base_wn); gh1[0] = acc[0]; gh1[1] = acc[1];
    PH_DRAIN(S0, base_wn);           gh2[0] = acc[0]; gh2[1] = acc[1];
    // ------- drained window: ring empty; all plain loads live here -------
    float dtn[4], mn[4];
    if (i < L_SEQ - 1) {
#pragma unroll
      for (int j = 0; j < 4; ++j) {
        int b = b0 + lg * 4 + j;
        mn[j] = (x[b * L_SEQ + i + 1] != 0) ? 1.f : 0.f;
        dtn[j] = fmaxf(t[b * L_SEQ + i + 1] - t[b * L_SEQ + i], 1e-6f);
      }
    } else {
#pragma unroll
      for (int j = 0; j < 4; ++j) { mn[j] = mj[j]; dtn[j] = dtj[j]; }
    }
    barrier_nd();                                  // all S0 reads done -> can rewrite

    // GRU epilogue (gi loaded inline; ring is empty)
#pragma unroll
    for (int nf = 0; nf < 2; ++nf) {
      int col = n0 + nf * 16 + lr;
      float br = bhhs[col], bz = bhhs[col + 512], bn = bhhs[col + 1024];
#pragma unroll
      for (int j = 0; j < 4; ++j) {
        const ushort_t* gp = gib + (size_t)(i * BATCH + b0 + lg * 4 + j) * 1536 + col;
        float gr_ = bf2f(__builtin_nontemporal_load(gp));
        float gz_ = bf2f(__builtin_nontemporal_load(gp + 512));
        float gn_ = bf2f(__builtin_nontemporal_load(gp + 1024));
        float rr = sigm_f(gr_ + gh0[nf][j] + br);
        float zz = sigm_f(gz_ + gh1[nf][j] + bz);
        float nn = tanh_f(gn_ + rr * (gh2[nf][j] + bn));
        float hnew = (1.f - zz) * nn + zz * h[nf][j];
        float hv = (mj[j] > 0.5f) ? hnew : h[nf][j];
        h[nf][j] = hv;
        *(ushort_t*)(S0 + aoff(lg * 4 + j, col)) = f2bf(hv);   // next step's A image
      }
    }
#pragma unroll
    for (int j = 0; j < 4; ++j) { dtj[j] = dtn[j]; mj[j] = mn[j]; }
  }

#pragma unroll
  for (int nf = 0; nf < 2; ++nf) {
    int col = n0 + nf * 16 + lr;
#pragma unroll
    for (int j = 0; j < 4; ++j) {
      int b = b0 + lg * 4 + j;
      out[(size_t)b * DIM + col] = h[nf][j];
    }
  }
}

extern "C" void kernel_launch(void* const* d_in, const int* in_sizes, int n_in,
                              void* d_out, int out_size, void* d_ws, size_t ws_size,
                              hipStream_t stream) {
  const float* t_   = (const float*)d_in[0];
  const float* emb  = (const float*)d_in[1];
  const float* Wih  = (const float*)d_in[2];
  const float* Whh  = (const float*)d_in[3];
  const float* bih  = (const float*)d_in[4];
  const float* bhh  = (const float*)d_in[5];
  const float* W1   = (const float*)d_in[6];
  const float* b1   = (const float*)d_in[7];
  const float* W2   = (const float*)d_in[8];
  const float* b2   = (const float*)d_in[9];
  const int*   x    = (const int*)d_in[10];
  float* out = (float*)d_out;
  (void)b2; (void)in_sizes; (void)n_in; (void)out_size; (void)ws_size;

  ushort_t* wsb = (ushort_t*)d_ws;                 // 2097152 ushorts of weight images
  ushort_t* gib = wsb + 2097152;                   // bf16 gi[L][B][1536]

  hipLaunchKernelGGL(prep_w, dim3(8192), dim3(256), 0, stream, W1, W2, Whh, Wih, wsb);
  hipLaunchKernelGGL(gi_gemm, dim3(1024, 6), dim3(256), 0, stream, emb, x, bih, wsb, gib);
  hipLaunchKernelGGL(scan_kernel, dim3(32), dim3(1024), 0, stream,
                     t_, x, wsb, b1, b2, bhh, gib, out);
}